// Round 21
// baseline (257.326 us; speedup 1.0000x reference)
//
#include <hip/hip_runtime.h>

// ---- raw bf16 bits as unsigned short ----
typedef unsigned short bf16_t;
typedef unsigned short u16x8 __attribute__((ext_vector_type(8)));
typedef unsigned short u16x4 __attribute__((ext_vector_type(4)));
typedef float f32x4 __attribute__((ext_vector_type(4)));

#define D_MODEL 1024
#define NHEAD 16
#define DHEAD 64
#define FF_DIM 4096
#define SEQ 2048
#define BATCH 2
#define LOG2E 1.44269504088896340736f
#define EXP2F(x) __builtin_amdgcn_exp2f(x)

#define GLOAD_LDS16(gp, lp)                                          \
  __builtin_amdgcn_global_load_lds(                                  \
      (const __attribute__((address_space(1))) void*)(gp),           \
      (__attribute__((address_space(3))) void*)(lp), 16, 0, 0)

static __device__ __forceinline__ float bf2f(bf16_t b) {
  union { unsigned u; float f; } x;
  x.u = ((unsigned)b) << 16;
  return x.f;
}
static __device__ __forceinline__ bf16_t f2bf(float f) {
  union { float f; unsigned u; } x;
  x.f = f;
  unsigned r = (x.u + 0x7fffu + ((x.u >> 16) & 1u)) >> 16;
  return (bf16_t)r;
}
// HW packed f32->bf16 (RNE), 1 instruction for 2 values [T12 recipe]
static __device__ __forceinline__ int cvtpk(float lo, float hi) {
  int r;
  asm("v_cvt_pk_bf16_f32 %0, %1, %2" : "=v"(r) : "v"(lo), "v"(hi));
  return r;
}
static __device__ __forceinline__ f32x4 mfma16(u16x8 a, u16x8 b, f32x4 c) {
  return __builtin_amdgcn_mfma_f32_16x16x32_bf16(a, b, c, 0, 0, 0);
}
static __device__ __forceinline__ u16x8 load8_f32(const float* q) {
  const float4 v0 = *(const float4*)(q);
  const float4 v1 = *(const float4*)(q + 4);
  u16x8 r;
  r[0] = f2bf(v0.x); r[1] = f2bf(v0.y); r[2] = f2bf(v0.z); r[3] = f2bf(v0.w);
  r[4] = f2bf(v1.x); r[5] = f2bf(v1.y); r[6] = f2bf(v1.z); r[7] = f2bf(v1.w);
  return r;
}

// ============================================================================
// fused fp32 -> bf16 conversion for ALL inputs, one dispatch (8192 blocks)
// ============================================================================
__global__ __launch_bounds__(256) void cvt_all(
    const float* __restrict__ src, bf16_t* __restrict__ dsrc,
    const float* __restrict__ qw, const float* __restrict__ kw,
    const float* __restrict__ vw, const float* __restrict__ ow,
    bf16_t* __restrict__ wqkv, bf16_t* __restrict__ owb,
    const float* __restrict__ w1, bf16_t* __restrict__ w1b,
    const float* __restrict__ w2, bf16_t* __restrict__ w2b) {
  const int b = blockIdx.x;
  const float* s;
  bf16_t* d;
  long off;
  if (b < 2048) {
    s = src; d = dsrc; off = (long)b * 2048;
  } else if (b < 4096) {
    const int seg = (b - 2048) >> 9, r = (b - 2048) & 511;
    s = seg == 0 ? qw : seg == 1 ? kw : seg == 2 ? vw : ow;
    d = (seg == 3) ? owb : wqkv + (long)seg * 1048576;
    off = (long)r * 2048;
  } else if (b < 6144) {
    s = w1; d = w1b; off = (long)(b - 4096) * 2048;
  } else {
    s = w2; d = w2b; off = (long)(b - 6144) * 2048;
  }
  const long i = off + threadIdx.x * 8;
  *(u16x8*)(d + i) = load8_f32(s + i);
}

// ============================================================================
// m97-structure GEMM, BK=64, swizzled staging (T21) + T3-minimum DOUBLE-
// BUFFERED pipeline: stage tile t+1 is issued BEFORE computing tile t; ONE
// barrier per K-tile (its vmcnt drain lands after compute hid the latency).
// 128x128 tile, global_load_lds width-16, LDS [2][128][64] chunk-XOR swizzle.
// XCD-chunked supertile decode.
// SMODE 0: C0[M,N]=act(.+bias); SMODE 3: fused QKV; SMODE 4: split-K4 bf16.
// ============================================================================
template <int SMODE>
__global__ __launch_bounds__(256) void gemm_lds(
    const bf16_t* __restrict__ A, const bf16_t* __restrict__ W,
    const float* __restrict__ bq_, const float* __restrict__ bk_,
    const float* __restrict__ bv_, bf16_t* __restrict__ C0,
    bf16_t* __restrict__ C1, bf16_t* __restrict__ C2,
    bf16_t* __restrict__ C3,
    int N, int Kseg, long lda, long ldw, int relu, float qscale,
    int gxs) {
  __shared__ bf16_t As[2][128 * 64];
  __shared__ bf16_t Bs[2][128 * 64];
  const int tid = threadIdx.x;
  const int lane = tid & 63;
  const int w = tid >> 6;
  const int wr = w >> 1, wc = w & 1;
  const int g = lane >> 4, c = lane & 15;

  const int per = (int)gridDim.x >> 3;
  const int gt = (blockIdx.x & 7) * per + (blockIdx.x >> 3);
  const int u = gt & 31;
  const int st = gt >> 5;
  const int sx = st % gxs;
  const int t2 = st / gxs;
  const int sy = t2 & 7;
  const int z = t2 >> 3;
  const long bm = (long)(sy * 4 + (u & 3)) * 128;
  const long bn = (long)(sx * 8 + (u >> 2)) * 128;
  const long koff = (long)z * Kseg;

  f32x4 acc[4][4];
#pragma unroll
  for (int i = 0; i < 4; ++i)
#pragma unroll
    for (int j = 0; j < 4; ++j) acc[i][j] = (f32x4){0.f, 0.f, 0.f, 0.f};

  const int ckey = c & 7;

  // staging helper: issue 8 global_load_lds for K-tile at kbase into buf
  auto stage = [&](int buf, long kbase) {
#pragma unroll
    for (int ld = 0; ld < 4; ++ld) {
      const int ch = ld * 256 + tid;
      const int row = ch >> 3;
      const int cc = (ch & 7) ^ (row & 7);
      GLOAD_LDS16(A + (bm + row) * lda + kbase + cc * 8,
                  As[buf] + (ld * 256 + w * 64) * 8);
    }
#pragma unroll
    for (int ld = 0; ld < 4; ++ld) {
      const int ch = ld * 256 + tid;
      const int row = ch >> 3;
      const int cc = (ch & 7) ^ (row & 7);
      GLOAD_LDS16(W + (bn + row) * ldw + kbase + cc * 8,
                  Bs[buf] + (ld * 256 + w * 64) * 8);
    }
  };

  // prologue: stage tile 0
  stage(0, koff);
  __syncthreads();

  int cur = 0;
  for (int k0 = 0; k0 < Kseg; k0 += 64) {
    // issue NEXT tile's loads early (fly during compute of current tile)
    if (k0 + 64 < Kseg) stage(cur ^ 1, koff + k0 + 64);
#pragma unroll
    for (int kk = 0; kk < 2; ++kk) {
      u16x8 af[4], bfv[4];
#pragma unroll
      for (int i = 0; i < 4; ++i)
        af[i] = *(const u16x8*)(
            As[cur] + ((wr * 64 + i * 16 + c) * 8 + ((kk * 4 + g) ^ ckey)) * 8);
#pragma unroll
      for (int j = 0; j < 4; ++j)
        bfv[j] = *(const u16x8*)(
            Bs[cur] + ((wc * 64 + j * 16 + c) * 8 + ((kk * 4 + g) ^ ckey)) * 8);
      __builtin_amdgcn_s_setprio(1);
#pragma unroll
      for (int i = 0; i < 4; ++i)
#pragma unroll
        for (int j = 0; j < 4; ++j)
          acc[i][j] = mfma16(af[i], bfv[j], acc[i][j]);
      __builtin_amdgcn_s_setprio(0);
    }
    __syncthreads();  // next-tile loads landed; all waves done with buf cur
    cur ^= 1;
  }

  bf16_t* __restrict__ pp =
      (z == 0) ? C0 : (z == 1) ? C1 : (z == 2) ? C2 : C3;
#pragma unroll
  for (int i = 0; i < 4; ++i) {
#pragma unroll
    for (int j = 0; j < 4; ++j) {
      const int nn = (int)bn + wc * 64 + j * 16 + c;
#pragma unroll
      for (int r = 0; r < 4; ++r) {
        const int mm = (int)bm + wr * 64 + i * 16 + g * 4 + r;
        if (SMODE == 0) {
          float v = acc[i][j][r] + bq_[nn];
          if (relu) v = fmaxf(v, 0.f);
          C0[(long)mm * N + nn] = f2bf(v);
        } else if (SMODE == 4) {
          pp[(long)mm * N + nn] = f2bf(acc[i][j][r]);
        } else {
          const int seg = nn >> 10;
          const int col = nn & 1023;
          const int h = col >> 6, dh = col & 63;
          const int b = mm >> 11, s = mm & 2047;
          if (seg == 0) {
            const float v = (acc[i][j][r] + bq_[col]) * qscale;
            C0[((((long)b * NHEAD + h) * SEQ + s) << 6) + dh] = f2bf(v);
          } else if (seg == 1) {
            const float v = acc[i][j][r] + bk_[col];
            C1[((((long)b * NHEAD + h) * SEQ + s) << 6) + dh] = f2bf(v);
          } else {
            const float v = acc[i][j][r] + bv_[col];
            C2[(((long)b * NHEAD + h) * DHEAD + dh) * SEQ + s] = f2bf(v);
          }
        }
      }
    }
  }
}

// ============================================================================
// stage a 64x64 bf16 tile into LDS linear [64][64] with per-row chunk XOR
// swizzle. KEY=0: key = row&7 (V). KEY=1: key = (row&3)|((row&8)>>1) (K).
// ============================================================================
template <int KEY>
static __device__ __forceinline__ void stage_tile(
    const bf16_t* __restrict__ gbase, long rstride, bf16_t* lds,
    int tid, int w) {
#pragma unroll
  for (int i = 0; i < 2; ++i) {
    const int row = i * 32 + (tid >> 3);
    const int key = KEY ? ((row & 3) | ((row & 8) >> 1)) : (row & 7);
    const int c4 = (tid & 7) ^ key;
    GLOAD_LDS16(gbase + (long)row * rstride + c4 * 8,
                lds + (i * 256 + w * 64) * 8);
  }
}

// ============================================================================
// Flash attention: swapped-QK, zero-shuffle PV (pi-permuted K rows), 32 q
// rows/wave, KVBLK=128, DOUBLE-BUFFERED K/V staging (stage t+1 overlaps
// compute of t; ONE barrier per tile), cvt_pk pack, defer-max, XCD swizzle.
// Q pre-scaled by 0.125*log2e (exp2 domain). LDS 64KB -> 2 blocks/CU.
// ============================================================================
__global__ __launch_bounds__(256, 2) void attn_fwd(
    const bf16_t* __restrict__ Q, const bf16_t* __restrict__ K,
    const bf16_t* __restrict__ Vt, bf16_t* __restrict__ O) {
  __shared__ bf16_t Ks[2][2][64 * 64];  // [buf][sub]
  __shared__ bf16_t Vs[2][2][64 * 64];
  const int tid = threadIdx.x;
  const int lane = tid & 63;
  const int w = tid >> 6;
  const int g = lane >> 4, c = lane & 15;
  const int lb = blockIdx.x;
  const int xcd = lb & 7, sl = lb >> 3;   // sl in [0,64)
  const int bh = xcd * 4 + (sl >> 4);     // 4 heads per XCD
  const int q0 = (sl & 15) * 128 + w * 32;
  const bf16_t* Qb = Q + (long)bh * SEQ * DHEAD;
  const bf16_t* Kb = K + (long)bh * SEQ * DHEAD;
  const bf16_t* Vb = Vt + (long)bh * DHEAD * SEQ;

  u16x8 bq[2][2];
#pragma unroll
  for (int qh = 0; qh < 2; ++qh) {
    bq[qh][0] = *(const u16x8*)(Qb + (q0 + qh * 16 + c) * DHEAD + g * 8);
    bq[qh][1] = *(const u16x8*)(Qb + (q0 + qh * 16 + c) * DHEAD + 32 + g * 8);
  }

  float m0 = -1e30f, m1 = -1e30f, lp0 = 0.f, lp1 = 0.f;
  f32x4 oacc[4][2];
#pragma unroll
  for (int d = 0; d < 4; ++d)
#pragma unroll
    for (int qh = 0; qh < 2; ++qh) oacc[d][qh] = (f32x4){0.f, 0.f, 0.f, 0.f};

  const int ck = c & 7;
  const int pr = ((c >> 2) << 3) | (c & 3);  // pi0(c); pi1 = pr + 4

  // prologue: stage tile 0 into buf 0
  stage_tile<1>(Kb, DHEAD, Ks[0][0], tid, w);
  stage_tile<1>(Kb + (long)64 * DHEAD, DHEAD, Ks[0][1], tid, w);
  stage_tile<0>(Vb, SEQ, Vs[0][0], tid, w);
  stage_tile<0>(Vb + 64, SEQ, Vs[0][1], tid, w);
  __syncthreads();

  int cur = 0;
  for (int t0 = 0; t0 < SEQ; t0 += 128) {
    // stage NEXT tile into the other buffer (overlaps this tile's compute)
    if (t0 + 128 < SEQ) {
      const int nb = cur ^ 1;
      const long tn = t0 + 128;
      stage_tile<1>(Kb + tn * DHEAD, DHEAD, Ks[nb][0], tid, w);
      stage_tile<1>(Kb + (tn + 64) * DHEAD, DHEAD, Ks[nb][1], tid, w);
      stage_tile<0>(Vb + tn, SEQ, Vs[nb][0], tid, w);
      stage_tile<0>(Vb + tn + 64, SEQ, Vs[nb][1], tid, w);
    }

#pragma unroll
    for (int sub = 0; sub < 2; ++sub) {
      const bf16_t* Ksb = Ks[cur][sub];
      const bf16_t* Vsb = Vs[cur][sub];

      f32x4 s[2][2][2];  // [tt][pi][qh]
#pragma unroll
      for (int tt = 0; tt < 2; ++tt) {
        const int rowA = (tt * 32 + pr) * 64;
        const int rowC = (tt * 32 + pr + 4) * 64;
        const u16x8 kA = *(const u16x8*)(Ksb + rowA + (g ^ ck) * 8);
        const u16x8 kB = *(const u16x8*)(Ksb + rowA + ((4 + g) ^ ck) * 8);
        const u16x8 kC = *(const u16x8*)(Ksb + rowC + (g ^ ck) * 8);
        const u16x8 kD = *(const u16x8*)(Ksb + rowC + ((4 + g) ^ ck) * 8);
        __builtin_amdgcn_s_setprio(1);
#pragma unroll
        for (int qh = 0; qh < 2; ++qh) {
          s[tt][0][qh] = mfma16(kA, bq[qh][0], (f32x4){0.f, 0.f, 0.f, 0.f});
          s[tt][0][qh] = mfma16(kB, bq[qh][1], s[tt][0][qh]);
          s[tt][1][qh] = mfma16(kC, bq[qh][0], (f32x4){0.f, 0.f, 0.f, 0.f});
          s[tt][1][qh] = mfma16(kD, bq[qh][1], s[tt][1][qh]);
        }
        __builtin_amdgcn_s_setprio(0);
      }

      float pmv[2];
#pragma unroll
      for (int qh = 0; qh < 2; ++qh) {
        float pm = s[0][0][qh][0];
#pragma unroll
        for (int tt = 0; tt < 2; ++tt)
#pragma unroll
          for (int pi = 0; pi < 2; ++pi)
#pragma unroll
            for (int r = 0; r < 4; ++r) pm = fmaxf(pm, s[tt][pi][qh][r]);
        pm = fmaxf(pm, __shfl_xor(pm, 16));
        pm = fmaxf(pm, __shfl_xor(pm, 32));
        pmv[qh] = pm;
      }
      if (!__all(pmv[0] <= m0 + 8.f && pmv[1] <= m1 + 8.f)) {
        const float mn0 = fmaxf(m0, pmv[0]);
        const float mn1 = fmaxf(m1, pmv[1]);
        const float f0 = EXP2F(m0 - mn0);
        const float f1 = EXP2F(m1 - mn1);
        m0 = mn0; m1 = mn1;
        lp0 *= f0; lp1 *= f1;
        float fb0[4], fb1[4];
#pragma unroll
        for (int r = 0; r < 4; ++r) {
          fb0[r] = __shfl(f0, 4 * g + r);
          fb1[r] = __shfl(f1, 4 * g + r);
        }
#pragma unroll
        for (int d = 0; d < 4; ++d)
#pragma unroll
          for (int r = 0; r < 4; ++r) {
            oacc[d][0][r] *= fb0[r];
            oacc[d][1][r] *= fb1[r];
          }
      }
      float ts0 = 0.f, ts1 = 0.f;
#pragma unroll
      for (int tt = 0; tt < 2; ++tt)
#pragma unroll
        for (int pi = 0; pi < 2; ++pi)
#pragma unroll
          for (int r = 0; r < 4; ++r) {
            s[tt][pi][0][r] = EXP2F(s[tt][pi][0][r] - m0);
            s[tt][pi][1][r] = EXP2F(s[tt][pi][1][r] - m1);
            ts0 += s[tt][pi][0][r];
            ts1 += s[tt][pi][1][r];
          }
      lp0 += ts0;
      lp1 += ts1;

      union { int u[4]; u16x8 v; } pu[2][2];  // [qh][tt]
#pragma unroll
      for (int qh = 0; qh < 2; ++qh)
#pragma unroll
        for (int tt = 0; tt < 2; ++tt) {
          pu[qh][tt].u[0] = cvtpk(s[tt][0][qh][0], s[tt][0][qh][1]);
          pu[qh][tt].u[1] = cvtpk(s[tt][0][qh][2], s[tt][0][qh][3]);
          pu[qh][tt].u[2] = cvtpk(s[tt][1][qh][0], s[tt][1][qh][1]);
          pu[qh][tt].u[3] = cvtpk(s[tt][1][qh][2], s[tt][1][qh][3]);
        }

#pragma unroll
      for (int d = 0; d < 4; ++d) {
        const int rowb = (d * 16 + c) * 64;
        const u16x8 v0 = *(const u16x8*)(Vsb + rowb + ((g ^ ck)) * 8);
        const u16x8 v1 = *(const u16x8*)(Vsb + rowb + (((4 + g) ^ ck)) * 8);
        __builtin_amdgcn_s_setprio(1);
        oacc[d][0] = mfma16(pu[0][0].v, v0, oacc[d][0]);
        oacc[d][0] = mfma16(pu[0][1].v, v1, oacc[d][0]);
        oacc[d][1] = mfma16(pu[1][0].v, v0, oacc[d][1]);
        oacc[d][1] = mfma16(pu[1][1].v, v1, oacc[d][1]);
        __builtin_amdgcn_s_setprio(0);
      }
    }

    __syncthreads();  // next-tile loads landed AND all waves done with buf cur
    cur ^= 1;
  }

  const int b = bh >> 4, h = bh & 15;
#pragma unroll
  for (int qh = 0; qh < 2; ++qh) {
    float lt = qh ? lp1 : lp0;
    lt += __shfl_xor(lt, 16);
    lt += __shfl_xor(lt, 32);
#pragma unroll
    for (int r = 0; r < 4; ++r) {
      const float inv = 1.f / __shfl(lt, 4 * g + r);
      const long base =
          ((long)b * SEQ + q0 + qh * 16 + g * 4 + r) * D_MODEL + h * DHEAD;
#pragma unroll
      for (int d = 0; d < 4; ++d)
        O[base + d * 16 + c] = f2bf(oacc[d][qh][r] * inv);
    }
  }
}

// ============================================================================
// Fused residual + LayerNorm: out = LN(X + Y)*gamma + beta.
// YPART=1: Y = Y0+Y1+Y2+Y3 + ybias (bf16 split-K4 partials, fixed order).
// ============================================================================
template <int XF32, int OUTF32, int YPART>
__global__ __launch_bounds__(256) void add_ln(
    const void* __restrict__ X, const bf16_t* __restrict__ Y0,
    const bf16_t* __restrict__ Y1, const bf16_t* __restrict__ Y2,
    const bf16_t* __restrict__ Y3, const float* __restrict__ ybias,
    const float* __restrict__ gamma, const float* __restrict__ beta,
    void* __restrict__ Out) {
  __shared__ float red[2][4];
  const int tid = threadIdx.x;
  const int lane = tid & 63, w = tid >> 6;
  const long base = (long)blockIdx.x * D_MODEL;

  float xv[4];
  if (XF32) {
    const float4 t = *(const float4*)((const float*)X + base + tid * 4);
    xv[0] = t.x; xv[1] = t.y; xv[2] = t.z; xv[3] = t.w;
  } else {
    const u16x4 t = *(const u16x4*)((const bf16_t*)X + base + tid * 4);
#pragma unroll
    for (int i = 0; i < 4; ++i) xv[i] = bf2f(t[i]);
  }
  float yv[4];
  if (YPART) {
    const u16x4 t0 = *(const u16x4*)(Y0 + base + tid * 4);
    const u16x4 t1 = *(const u16x4*)(Y1 + base + tid * 4);
    const u16x4 t2 = *(const u16x4*)(Y2 + base + tid * 4);
    const u16x4 t3 = *(const u16x4*)(Y3 + base + tid * 4);
    const float4 bb = *(const float4*)(ybias + tid * 4);
#pragma unroll
    for (int i = 0; i < 4; ++i)
      yv[i] = ((bf2f(t0[i]) + bf2f(t1[i])) + (bf2f(t2[i]) + bf2f(t3[i]))) +
              ((const float*)&bb)[i];
  } else {
    const u16x4 t = *(const u16x4*)(Y0 + base + tid * 4);
#pragma unroll
    for (int i = 0; i < 4; ++i) yv[i] = bf2f(t[i]);
  }
  float v[4], s = 0.f, s2 = 0.f;
#pragma unroll
  for (int i = 0; i < 4; ++i) {
    const float t = xv[i] + yv[i];
    v[i] = t;
    s += t;
    s2 += t * t;
  }
#pragma unroll
  for (int off = 32; off; off >>= 1) {
    s += __shfl_xor(s, off);
    s2 += __shfl_xor(s2, off);
  }
  if (lane == 0) { red[0][w] = s; red[1][w] = s2; }
  __syncthreads();
  s = red[0][0] + red[0][1] + red[0][2] + red[0][3];
  s2 = red[1][0] + red[1][1] + red[1][2] + red[1][3];
  const float mu = s * (1.f / D_MODEL);
  const float var = s2 * (1.f / D_MODEL) - mu * mu;
  const float inv = rsqrtf(var + 1e-5f);
  const float4 gv = *(const float4*)(gamma + tid * 4);
  const float4 bv = *(const float4*)(beta + tid * 4);
  const float o0 = (v[0] - mu) * inv * gv.x + bv.x;
  const float o1 = (v[1] - mu) * inv * gv.y + bv.y;
  const float o2 = (v[2] - mu) * inv * gv.z + bv.z;
  const float o3 = (v[3] - mu) * inv * gv.w + bv.w;
  if (OUTF32) {
    float4 ov; ov.x = o0; ov.y = o1; ov.z = o2; ov.w = o3;
    *(float4*)((float*)Out + base + tid * 4) = ov;
  } else {
    u16x4 ov;
    ov[0] = f2bf(o0); ov[1] = f2bf(o1); ov[2] = f2bf(o2); ov[3] = f2bf(o3);
    *(u16x4*)((bf16_t*)Out + base + tid * 4) = ov;
  }
}

// ============================================================================
extern "C" void kernel_launch(void* const* d_in, const int* in_sizes, int n_in,
                              void* d_out, int out_size, void* d_ws, size_t ws_size,
                              hipStream_t stream) {
  const float* src = (const float*)d_in[0];
  const float* qw = (const float*)d_in[1];
  const float* qb = (const float*)d_in[2];
  const float* kw = (const float*)d_in[3];
  const float* kb = (const float*)d_in[4];
  const float* vw = (const float*)d_in[5];
  const float* vb = (const float*)d_in[6];
  const float* ow = (const float*)d_in[7];
  const float* ob = (const float*)d_in[8];
  const float* w1 = (const float*)d_in[9];
  const float* b1 = (const float*)d_in[10];
  const float* w2 = (const float*)d_in[11];
  const float* b2 = (const float*)d_in[12];
  const float* gam1 = (const float*)d_in[13];
  const float* bet1 = (const float*)d_in[14];
  const float* gam2 = (const float*)d_in[15];
  const float* bet2 = (const float*)d_in[16];

  char* ws = (char*)d_ws;
  const long MB = 1024 * 1024;
  // timeline-overlaid regions (peak 88MB):
  bf16_t* Qw   = (bf16_t*)(ws + 0 * MB);   // 8MB   (dead after attn)
  bf16_t* Kw   = (bf16_t*)(ws + 8 * MB);   // 8MB   (dead after attn)
  bf16_t* Vt   = (bf16_t*)(ws + 16 * MB);  // 8MB   (dead after attn)
  bf16_t* A1   = (bf16_t*)(ws + 24 * MB);  // 8MB   (dead after o-proj)
  bf16_t* X1   = (bf16_t*)(ws + 40 * MB);  // 8MB   post-LN1
  bf16_t* srcB = (bf16_t*)(ws + 48 * MB);  // 8MB   (dead after QKV)
  bf16_t* Wqkv = (bf16_t*)(ws + 56 * MB);  // 6MB   (dead after QKV)
  bf16_t* OWb  = (bf16_t*)(ws + 62 * MB);  // 2MB   (dead after o-proj)
  bf16_t* W1b  = (bf16_t*)(ws + 64 * MB);  // 8MB   (dead after FF1)
  bf16_t* W2b  = (bf16_t*)(ws + 72 * MB);  // 8MB
  // o-proj bf16 partials (alive o-proj..LN1; over dead Qw/Kw/Vt/srcB):
  bf16_t* Poa  = (bf16_t*)(ws + 0 * MB);
  bf16_t* Pob  = (bf16_t*)(ws + 8 * MB);
  bf16_t* Poc  = (bf16_t*)(ws + 16 * MB);
  bf16_t* Pod  = (bf16_t*)(ws + 48 * MB);
  bf16_t* F1   = (bf16_t*)(ws + 0 * MB);   // ff1 32MB (over Poa-c/A1, after LN1)
  // ff2 bf16 partials (alive ff2..LN2; over dead srcB/Wqkv/OWb/W1b + 80MB):
  bf16_t* Pfa  = (bf16_t*)(ws + 48 * MB);
  bf16_t* Pfb  = (bf16_t*)(ws + 56 * MB);
  bf16_t* Pfc  = (bf16_t*)(ws + 64 * MB);
  bf16_t* Pfd  = (bf16_t*)(ws + 80 * MB);

  const int M = BATCH * SEQ;  // 4096
  dim3 blk(256);
  const float qscale = 0.125f * LOG2E;

  // all fp32->bf16 conversions in ONE dispatch
  cvt_all<<<dim3(8192), blk, 0, stream>>>(
      src, srcB, qw, kw, vw, ow, Wqkv, OWb, w1, W1b, w2, W2b);

  // QKV: N=3072 (gxs=3), 768 blocks
  gemm_lds<3><<<dim3(768), blk, 0, stream>>>(
      srcB, Wqkv, qb, kb, vb, Qw, Kw, Vt, (bf16_t*)0,
      3072, 1024, 1024, 1024, 0, qscale, 3);
  attn_fwd<<<dim3(512), blk, 0, stream>>>(Qw, Kw, Vt, A1);
  // o-proj: N=1024 (gxs=1), split-K4, 1024 blocks (4/CU)
  gemm_lds<4><<<dim3(1024), blk, 0, stream>>>(
      A1, OWb, ob, ob, ob, Poa, Pob, Poc, Pod,
      1024, 256, 1024, 1024, 0, 1.f, 1);
  add_ln<1, 0, 1><<<dim3(M), blk, 0, stream>>>(
      src, Poa, Pob, Poc, Pod, ob, gam1, bet1, X1);
  // FF1: N=4096 (gxs=4), 1024 blocks
  gemm_lds<0><<<dim3(1024), blk, 0, stream>>>(
      X1, W1b, b1, b1, b1, F1, F1, F1, (bf16_t*)0,
      4096, 1024, 1024, 1024, 1, 1.f, 4);
  // FF2: N=1024 (gxs=1), split-K4, 1024 blocks (4/CU)
  gemm_lds<4><<<dim3(1024), blk, 0, stream>>>(
      F1, W2b, b2, b2, b2, Pfa, Pfb, Pfc, Pfd,
      1024, 1024, 4096, 4096, 0, 1.f, 1);
  add_ln<0, 1, 1><<<dim3(M), blk, 0, stream>>>(
      X1, Pfa, Pfb, Pfc, Pfd, b2, gam2, bet2, d_out);
}

// Round 22
// 246.899 us; speedup vs baseline: 1.0422x; 1.0422x over previous
//
#include <hip/hip_runtime.h>

// ---- raw bf16 bits as unsigned short ----
typedef unsigned short bf16_t;
typedef unsigned short u16x8 __attribute__((ext_vector_type(8)));
typedef unsigned short u16x4 __attribute__((ext_vector_type(4)));
typedef float f32x4 __attribute__((ext_vector_type(4)));

#define D_MODEL 1024
#define NHEAD 16
#define DHEAD 64
#define FF_DIM 4096
#define SEQ 2048
#define BATCH 2
#define LOG2E 1.44269504088896340736f
#define EXP2F(x) __builtin_amdgcn_exp2f(x)

#define GLOAD_LDS16(gp, lp)                                          \
  __builtin_amdgcn_global_load_lds(                                  \
      (const __attribute__((address_space(1))) void*)(gp),           \
      (__attribute__((address_space(3))) void*)(lp), 16, 0, 0)

static __device__ __forceinline__ float bf2f(bf16_t b) {
  union { unsigned u; float f; } x;
  x.u = ((unsigned)b) << 16;
  return x.f;
}
static __device__ __forceinline__ bf16_t f2bf(float f) {
  union { float f; unsigned u; } x;
  x.f = f;
  unsigned r = (x.u + 0x7fffu + ((x.u >> 16) & 1u)) >> 16;
  return (bf16_t)r;
}
// HW packed f32->bf16 (RNE), 1 instruction for 2 values [T12 recipe]
static __device__ __forceinline__ int cvtpk(float lo, float hi) {
  int r;
  asm("v_cvt_pk_bf16_f32 %0, %1, %2" : "=v"(r) : "v"(lo), "v"(hi));
  return r;
}
static __device__ __forceinline__ f32x4 mfma16(u16x8 a, u16x8 b, f32x4 c) {
  return __builtin_amdgcn_mfma_f32_16x16x32_bf16(a, b, c, 0, 0, 0);
}
static __device__ __forceinline__ u16x8 load8_f32(const float* q) {
  const float4 v0 = *(const float4*)(q);
  const float4 v1 = *(const float4*)(q + 4);
  u16x8 r;
  r[0] = f2bf(v0.x); r[1] = f2bf(v0.y); r[2] = f2bf(v0.z); r[3] = f2bf(v0.w);
  r[4] = f2bf(v1.x); r[5] = f2bf(v1.y); r[6] = f2bf(v1.z); r[7] = f2bf(v1.w);
  return r;
}

// ============================================================================
// fused fp32 -> bf16 conversion for ALL inputs, one dispatch (8192 blocks)
// ============================================================================
__global__ __launch_bounds__(256) void cvt_all(
    const float* __restrict__ src, bf16_t* __restrict__ dsrc,
    const float* __restrict__ qw, const float* __restrict__ kw,
    const float* __restrict__ vw, const float* __restrict__ ow,
    bf16_t* __restrict__ wqkv, bf16_t* __restrict__ owb,
    const float* __restrict__ w1, bf16_t* __restrict__ w1b,
    const float* __restrict__ w2, bf16_t* __restrict__ w2b) {
  const int b = blockIdx.x;
  const float* s;
  bf16_t* d;
  long off;
  if (b < 2048) {
    s = src; d = dsrc; off = (long)b * 2048;
  } else if (b < 4096) {
    const int seg = (b - 2048) >> 9, r = (b - 2048) & 511;
    s = seg == 0 ? qw : seg == 1 ? kw : seg == 2 ? vw : ow;
    d = (seg == 3) ? owb : wqkv + (long)seg * 1048576;
    off = (long)r * 2048;
  } else if (b < 6144) {
    s = w1; d = w1b; off = (long)(b - 4096) * 2048;
  } else {
    s = w2; d = w2b; off = (long)(b - 6144) * 2048;
  }
  const long i = off + threadIdx.x * 8;
  *(u16x8*)(d + i) = load8_f32(s + i);
}

// ============================================================================
// m97-structure GEMM, BK=64, swizzled staging (T21): operands bf16, bias fp32.
// 128x128 tile, global_load_lds width-16, LDS [128][64] with chunk-XOR
// swizzle -> conflict-free ds_read_b128. XCD-chunked supertile decode.
// SMODE 0: C0[M,N]=act(.+bias); SMODE 3: fused QKV; SMODE 4: split-K4 bf16.
// ============================================================================
template <int SMODE>
__global__ __launch_bounds__(256) void gemm_lds(
    const bf16_t* __restrict__ A, const bf16_t* __restrict__ W,
    const float* __restrict__ bq_, const float* __restrict__ bk_,
    const float* __restrict__ bv_, bf16_t* __restrict__ C0,
    bf16_t* __restrict__ C1, bf16_t* __restrict__ C2,
    bf16_t* __restrict__ C3,
    int N, int Kseg, long lda, long ldw, int relu, float qscale,
    int gxs) {
  __shared__ bf16_t As[128 * 64];
  __shared__ bf16_t Bs[128 * 64];
  const int tid = threadIdx.x;
  const int lane = tid & 63;
  const int w = tid >> 6;
  const int wr = w >> 1, wc = w & 1;
  const int g = lane >> 4, c = lane & 15;

  const int per = (int)gridDim.x >> 3;
  const int gt = (blockIdx.x & 7) * per + (blockIdx.x >> 3);
  const int u = gt & 31;
  const int st = gt >> 5;
  const int sx = st % gxs;
  const int t2 = st / gxs;
  const int sy = t2 & 7;
  const int z = t2 >> 3;
  const long bm = (long)(sy * 4 + (u & 3)) * 128;
  const long bn = (long)(sx * 8 + (u >> 2)) * 128;
  const long koff = (long)z * Kseg;

  f32x4 acc[4][4];
#pragma unroll
  for (int i = 0; i < 4; ++i)
#pragma unroll
    for (int j = 0; j < 4; ++j) acc[i][j] = (f32x4){0.f, 0.f, 0.f, 0.f};

  const int ckey = c & 7;

  for (int k0 = 0; k0 < Kseg; k0 += 64) {
    __syncthreads();
#pragma unroll
    for (int ld = 0; ld < 4; ++ld) {
      const int ch = ld * 256 + tid;
      const int row = ch >> 3;
      const int cc = (ch & 7) ^ (row & 7);
      GLOAD_LDS16(A + (bm + row) * lda + koff + k0 + cc * 8,
                  As + (ld * 256 + w * 64) * 8);
    }
#pragma unroll
    for (int ld = 0; ld < 4; ++ld) {
      const int ch = ld * 256 + tid;
      const int row = ch >> 3;
      const int cc = (ch & 7) ^ (row & 7);
      GLOAD_LDS16(W + (bn + row) * ldw + koff + k0 + cc * 8,
                  Bs + (ld * 256 + w * 64) * 8);
    }
    __syncthreads();
#pragma unroll
    for (int kk = 0; kk < 2; ++kk) {
      u16x8 af[4], bfv[4];
#pragma unroll
      for (int i = 0; i < 4; ++i)
        af[i] = *(const u16x8*)(
            As + ((wr * 64 + i * 16 + c) * 8 + ((kk * 4 + g) ^ ckey)) * 8);
#pragma unroll
      for (int j = 0; j < 4; ++j)
        bfv[j] = *(const u16x8*)(
            Bs + ((wc * 64 + j * 16 + c) * 8 + ((kk * 4 + g) ^ ckey)) * 8);
      __builtin_amdgcn_s_setprio(1);
#pragma unroll
      for (int i = 0; i < 4; ++i)
#pragma unroll
        for (int j = 0; j < 4; ++j)
          acc[i][j] = mfma16(af[i], bfv[j], acc[i][j]);
      __builtin_amdgcn_s_setprio(0);
    }
  }

  bf16_t* __restrict__ pp =
      (z == 0) ? C0 : (z == 1) ? C1 : (z == 2) ? C2 : C3;
#pragma unroll
  for (int i = 0; i < 4; ++i) {
#pragma unroll
    for (int j = 0; j < 4; ++j) {
      const int nn = (int)bn + wc * 64 + j * 16 + c;
#pragma unroll
      for (int r = 0; r < 4; ++r) {
        const int mm = (int)bm + wr * 64 + i * 16 + g * 4 + r;
        if (SMODE == 0) {
          float v = acc[i][j][r] + bq_[nn];
          if (relu) v = fmaxf(v, 0.f);
          C0[(long)mm * N + nn] = f2bf(v);
        } else if (SMODE == 4) {
          pp[(long)mm * N + nn] = f2bf(acc[i][j][r]);
        } else {
          const int seg = nn >> 10;
          const int col = nn & 1023;
          const int h = col >> 6, dh = col & 63;
          const int b = mm >> 11, s = mm & 2047;
          if (seg == 0) {
            const float v = (acc[i][j][r] + bq_[col]) * qscale;
            C0[((((long)b * NHEAD + h) * SEQ + s) << 6) + dh] = f2bf(v);
          } else if (seg == 1) {
            const float v = acc[i][j][r] + bk_[col];
            C1[((((long)b * NHEAD + h) * SEQ + s) << 6) + dh] = f2bf(v);
          } else {
            const float v = acc[i][j][r] + bv_[col];
            C2[(((long)b * NHEAD + h) * DHEAD + dh) * SEQ + s] = f2bf(v);
          }
        }
      }
    }
  }
}

// ============================================================================
// stage a 64x64 bf16 tile into LDS linear [64][64] with per-row chunk XOR
// swizzle. KEY=0: key = row&7 (V). KEY=1: key = (row&3)|((row&8)>>1) (K).
// ============================================================================
template <int KEY>
static __device__ __forceinline__ void stage_tile(
    const bf16_t* __restrict__ gbase, long rstride, bf16_t* lds,
    int tid, int w) {
#pragma unroll
  for (int i = 0; i < 2; ++i) {
    const int row = i * 32 + (tid >> 3);
    const int key = KEY ? ((row & 3) | ((row & 8) >> 1)) : (row & 7);
    const int c4 = (tid & 7) ^ key;
    GLOAD_LDS16(gbase + (long)row * rstride + c4 * 8,
                lds + (i * 256 + w * 64) * 8);
  }
}

// ============================================================================
// Flash attention: swapped-QK, zero-shuffle PV (pi-permuted K rows), 32 q
// rows/wave, KVBLK=128, cvt_pk pack, defer-max, XCD-aware swizzle.
// Q pre-scaled by 0.125*log2e (exp2 domain).
// ============================================================================
__global__ __launch_bounds__(256, 2) void attn_fwd(
    const bf16_t* __restrict__ Q, const bf16_t* __restrict__ K,
    const bf16_t* __restrict__ Vt, bf16_t* __restrict__ O) {
  __shared__ bf16_t Ks0[64 * 64];
  __shared__ bf16_t Ks1[64 * 64];
  __shared__ bf16_t Vs0[64 * 64];
  __shared__ bf16_t Vs1[64 * 64];
  const int tid = threadIdx.x;
  const int lane = tid & 63;
  const int w = tid >> 6;
  const int g = lane >> 4, c = lane & 15;
  const int lb = blockIdx.x;
  const int xcd = lb & 7, sl = lb >> 3;
  const int bh = xcd * 4 + (sl >> 4);
  const int q0 = (sl & 15) * 128 + w * 32;
  const bf16_t* Qb = Q + (long)bh * SEQ * DHEAD;
  const bf16_t* Kb = K + (long)bh * SEQ * DHEAD;
  const bf16_t* Vb = Vt + (long)bh * DHEAD * SEQ;

  u16x8 bq[2][2];
#pragma unroll
  for (int qh = 0; qh < 2; ++qh) {
    bq[qh][0] = *(const u16x8*)(Qb + (q0 + qh * 16 + c) * DHEAD + g * 8);
    bq[qh][1] = *(const u16x8*)(Qb + (q0 + qh * 16 + c) * DHEAD + 32 + g * 8);
  }

  float m0 = -1e30f, m1 = -1e30f, lp0 = 0.f, lp1 = 0.f;
  f32x4 oacc[4][2];
#pragma unroll
  for (int d = 0; d < 4; ++d)
#pragma unroll
    for (int qh = 0; qh < 2; ++qh) oacc[d][qh] = (f32x4){0.f, 0.f, 0.f, 0.f};

  const int ck = c & 7;
  const int pr = ((c >> 2) << 3) | (c & 3);

  for (int t0 = 0; t0 < SEQ; t0 += 128) {
    __syncthreads();
    stage_tile<1>(Kb + (long)t0 * DHEAD, DHEAD, Ks0, tid, w);
    stage_tile<1>(Kb + (long)(t0 + 64) * DHEAD, DHEAD, Ks1, tid, w);
    stage_tile<0>(Vb + t0, SEQ, Vs0, tid, w);
    stage_tile<0>(Vb + t0 + 64, SEQ, Vs1, tid, w);
    __syncthreads();

#pragma unroll
    for (int sub = 0; sub < 2; ++sub) {
      const bf16_t* Ks = sub ? Ks1 : Ks0;
      const bf16_t* Vs = sub ? Vs1 : Vs0;

      f32x4 s[2][2][2];
#pragma unroll
      for (int tt = 0; tt < 2; ++tt) {
        const int rowA = (tt * 32 + pr) * 64;
        const int rowC = (tt * 32 + pr + 4) * 64;
        const u16x8 kA = *(const u16x8*)(Ks + rowA + (g ^ ck) * 8);
        const u16x8 kB = *(const u16x8*)(Ks + rowA + ((4 + g) ^ ck) * 8);
        const u16x8 kC = *(const u16x8*)(Ks + rowC + (g ^ ck) * 8);
        const u16x8 kD = *(const u16x8*)(Ks + rowC + ((4 + g) ^ ck) * 8);
        __builtin_amdgcn_s_setprio(1);
#pragma unroll
        for (int qh = 0; qh < 2; ++qh) {
          s[tt][0][qh] = mfma16(kA, bq[qh][0], (f32x4){0.f, 0.f, 0.f, 0.f});
          s[tt][0][qh] = mfma16(kB, bq[qh][1], s[tt][0][qh]);
          s[tt][1][qh] = mfma16(kC, bq[qh][0], (f32x4){0.f, 0.f, 0.f, 0.f});
          s[tt][1][qh] = mfma16(kD, bq[qh][1], s[tt][1][qh]);
        }
        __builtin_amdgcn_s_setprio(0);
      }

      float pmv[2];
#pragma unroll
      for (int qh = 0; qh < 2; ++qh) {
        float pm = s[0][0][qh][0];
#pragma unroll
        for (int tt = 0; tt < 2; ++tt)
#pragma unroll
          for (int pi = 0; pi < 2; ++pi)
#pragma unroll
            for (int r = 0; r < 4; ++r) pm = fmaxf(pm, s[tt][pi][qh][r]);
        pm = fmaxf(pm, __shfl_xor(pm, 16));
        pm = fmaxf(pm, __shfl_xor(pm, 32));
        pmv[qh] = pm;
      }
      if (!__all(pmv[0] <= m0 + 8.f && pmv[1] <= m1 + 8.f)) {
        const float mn0 = fmaxf(m0, pmv[0]);
        const float mn1 = fmaxf(m1, pmv[1]);
        const float f0 = EXP2F(m0 - mn0);
        const float f1 = EXP2F(m1 - mn1);
        m0 = mn0; m1 = mn1;
        lp0 *= f0; lp1 *= f1;
        float fb0[4], fb1[4];
#pragma unroll
        for (int r = 0; r < 4; ++r) {
          fb0[r] = __shfl(f0, 4 * g + r);
          fb1[r] = __shfl(f1, 4 * g + r);
        }
#pragma unroll
        for (int d = 0; d < 4; ++d)
#pragma unroll
          for (int r = 0; r < 4; ++r) {
            oacc[d][0][r] *= fb0[r];
            oacc[d][1][r] *= fb1[r];
          }
      }
      float ts0 = 0.f, ts1 = 0.f;
#pragma unroll
      for (int tt = 0; tt < 2; ++tt)
#pragma unroll
        for (int pi = 0; pi < 2; ++pi)
#pragma unroll
          for (int r = 0; r < 4; ++r) {
            s[tt][pi][0][r] = EXP2F(s[tt][pi][0][r] - m0);
            s[tt][pi][1][r] = EXP2F(s[tt][pi][1][r] - m1);
            ts0 += s[tt][pi][0][r];
            ts1 += s[tt][pi][1][r];
          }
      lp0 += ts0;
      lp1 += ts1;

      union { int u[4]; u16x8 v; } pu[2][2];
#pragma unroll
      for (int qh = 0; qh < 2; ++qh)
#pragma unroll
        for (int tt = 0; tt < 2; ++tt) {
          pu[qh][tt].u[0] = cvtpk(s[tt][0][qh][0], s[tt][0][qh][1]);
          pu[qh][tt].u[1] = cvtpk(s[tt][0][qh][2], s[tt][0][qh][3]);
          pu[qh][tt].u[2] = cvtpk(s[tt][1][qh][0], s[tt][1][qh][1]);
          pu[qh][tt].u[3] = cvtpk(s[tt][1][qh][2], s[tt][1][qh][3]);
        }

#pragma unroll
      for (int d = 0; d < 4; ++d) {
        const int rowb = (d * 16 + c) * 64;
        const u16x8 v0 = *(const u16x8*)(Vs + rowb + ((g ^ ck)) * 8);
        const u16x8 v1 = *(const u16x8*)(Vs + rowb + (((4 + g) ^ ck)) * 8);
        __builtin_amdgcn_s_setprio(1);
        oacc[d][0] = mfma16(pu[0][0].v, v0, oacc[d][0]);
        oacc[d][0] = mfma16(pu[0][1].v, v1, oacc[d][0]);
        oacc[d][1] = mfma16(pu[1][0].v, v0, oacc[d][1]);
        oacc[d][1] = mfma16(pu[1][1].v, v1, oacc[d][1]);
        __builtin_amdgcn_s_setprio(0);
      }
    }
  }

  const int b = bh >> 4, h = bh & 15;
#pragma unroll
  for (int qh = 0; qh < 2; ++qh) {
    float lt = qh ? lp1 : lp0;
    lt += __shfl_xor(lt, 16);
    lt += __shfl_xor(lt, 32);
#pragma unroll
    for (int r = 0; r < 4; ++r) {
      const float inv = 1.f / __shfl(lt, 4 * g + r);
      const long base =
          ((long)b * SEQ + q0 + qh * 16 + g * 4 + r) * D_MODEL + h * DHEAD;
#pragma unroll
      for (int d = 0; d < 4; ++d)
        O[base + d * 16 + c] = f2bf(oacc[d][qh][r] * inv);
    }
  }
}

// ============================================================================
// Fused residual + LayerNorm: out = LN(X + Y)*gamma + beta.
// YPART=1: Y = Y0+Y1+Y2+Y3 + ybias (bf16 split-K4 partials, fixed order).
// ============================================================================
template <int XF32, int OUTF32, int YPART>
__global__ __launch_bounds__(256) void add_ln(
    const void* __restrict__ X, const bf16_t* __restrict__ Y0,
    const bf16_t* __restrict__ Y1, const bf16_t* __restrict__ Y2,
    const bf16_t* __restrict__ Y3, const float* __restrict__ ybias,
    const float* __restrict__ gamma, const float* __restrict__ beta,
    void* __restrict__ Out) {
  __shared__ float red[2][4];
  const int tid = threadIdx.x;
  const int lane = tid & 63, w = tid >> 6;
  const long base = (long)blockIdx.x * D_MODEL;

  float xv[4];
  if (XF32) {
    const float4 t = *(const float4*)((const float*)X + base + tid * 4);
    xv[0] = t.x; xv[1] = t.y; xv[2] = t.z; xv[3] = t.w;
  } else {
    const u16x4 t = *(const u16x4*)((const bf16_t*)X + base + tid * 4);
#pragma unroll
    for (int i = 0; i < 4; ++i) xv[i] = bf2f(t[i]);
  }
  float yv[4];
  if (YPART) {
    const u16x4 t0 = *(const u16x4*)(Y0 + base + tid * 4);
    const u16x4 t1 = *(const u16x4*)(Y1 + base + tid * 4);
    const u16x4 t2 = *(const u16x4*)(Y2 + base + tid * 4);
    const u16x4 t3 = *(const u16x4*)(Y3 + base + tid * 4);
    const float4 bb = *(const float4*)(ybias + tid * 4);
#pragma unroll
    for (int i = 0; i < 4; ++i)
      yv[i] = ((bf2f(t0[i]) + bf2f(t1[i])) + (bf2f(t2[i]) + bf2f(t3[i]))) +
              ((const float*)&bb)[i];
  } else {
    const u16x4 t = *(const u16x4*)(Y0 + base + tid * 4);
#pragma unroll
    for (int i = 0; i < 4; ++i) yv[i] = bf2f(t[i]);
  }
  float v[4], s = 0.f, s2 = 0.f;
#pragma unroll
  for (int i = 0; i < 4; ++i) {
    const float t = xv[i] + yv[i];
    v[i] = t;
    s += t;
    s2 += t * t;
  }
#pragma unroll
  for (int off = 32; off; off >>= 1) {
    s += __shfl_xor(s, off);
    s2 += __shfl_xor(s2, off);
  }
  if (lane == 0) { red[0][w] = s; red[1][w] = s2; }
  __syncthreads();
  s = red[0][0] + red[0][1] + red[0][2] + red[0][3];
  s2 = red[1][0] + red[1][1] + red[1][2] + red[1][3];
  const float mu = s * (1.f / D_MODEL);
  const float var = s2 * (1.f / D_MODEL) - mu * mu;
  const float inv = rsqrtf(var + 1e-5f);
  const float4 gv = *(const float4*)(gamma + tid * 4);
  const float4 bv = *(const float4*)(beta + tid * 4);
  const float o0 = (v[0] - mu) * inv * gv.x + bv.x;
  const float o1 = (v[1] - mu) * inv * gv.y + bv.y;
  const float o2 = (v[2] - mu) * inv * gv.z + bv.z;
  const float o3 = (v[3] - mu) * inv * gv.w + bv.w;
  if (OUTF32) {
    float4 ov; ov.x = o0; ov.y = o1; ov.z = o2; ov.w = o3;
    *(float4*)((float*)Out + base + tid * 4) = ov;
  } else {
    u16x4 ov;
    ov[0] = f2bf(o0); ov[1] = f2bf(o1); ov[2] = f2bf(o2); ov[3] = f2bf(o3);
    *(u16x4*)((bf16_t*)Out + base + tid * 4) = ov;
  }
}

// ============================================================================
extern "C" void kernel_launch(void* const* d_in, const int* in_sizes, int n_in,
                              void* d_out, int out_size, void* d_ws, size_t ws_size,
                              hipStream_t stream) {
  const float* src = (const float*)d_in[0];
  const float* qw = (const float*)d_in[1];
  const float* qb = (const float*)d_in[2];
  const float* kw = (const float*)d_in[3];
  const float* kb = (const float*)d_in[4];
  const float* vw = (const float*)d_in[5];
  const float* vb = (const float*)d_in[6];
  const float* ow = (const float*)d_in[7];
  const float* ob = (const float*)d_in[8];
  const float* w1 = (const float*)d_in[9];
  const float* b1 = (const float*)d_in[10];
  const float* w2 = (const float*)d_in[11];
  const float* b2 = (const float*)d_in[12];
  const float* gam1 = (const float*)d_in[13];
  const float* bet1 = (const float*)d_in[14];
  const float* gam2 = (const float*)d_in[15];
  const float* bet2 = (const float*)d_in[16];

  char* ws = (char*)d_ws;
  const long MB = 1024 * 1024;
  // timeline-overlaid regions (peak 88MB):
  bf16_t* Qw   = (bf16_t*)(ws + 0 * MB);   // 8MB   (dead after attn)
  bf16_t* Kw   = (bf16_t*)(ws + 8 * MB);   // 8MB   (dead after attn)
  bf16_t* Vt   = (bf16_t*)(ws + 16 * MB);  // 8MB   (dead after attn)
  bf16_t* A1   = (bf16_t*)(ws + 24 * MB);  // 8MB   (dead after o-proj)
  bf16_t* X1   = (bf16_t*)(ws + 40 * MB);  // 8MB   post-LN1
  bf16_t* srcB = (bf16_t*)(ws + 48 * MB);  // 8MB   (dead after QKV)
  bf16_t* Wqkv = (bf16_t*)(ws + 56 * MB);  // 6MB   (dead after QKV)
  bf16_t* OWb  = (bf16_t*)(ws + 62 * MB);  // 2MB   (dead after o-proj)
  bf16_t* W1b  = (bf16_t*)(ws + 64 * MB);  // 8MB   (dead after FF1)
  bf16_t* W2b  = (bf16_t*)(ws + 72 * MB);  // 8MB
  // o-proj bf16 partials (alive o-proj..LN1; over dead Qw/Kw/Vt/srcB):
  bf16_t* Poa  = (bf16_t*)(ws + 0 * MB);
  bf16_t* Pob  = (bf16_t*)(ws + 8 * MB);
  bf16_t* Poc  = (bf16_t*)(ws + 16 * MB);
  bf16_t* Pod  = (bf16_t*)(ws + 48 * MB);
  bf16_t* F1   = (bf16_t*)(ws + 0 * MB);   // ff1 32MB (over Poa-c/A1, after LN1)
  // ff2 bf16 partials (alive ff2..LN2; over dead srcB/Wqkv/OWb/W1b + 80MB):
  bf16_t* Pfa  = (bf16_t*)(ws + 48 * MB);
  bf16_t* Pfb  = (bf16_t*)(ws + 56 * MB);
  bf16_t* Pfc  = (bf16_t*)(ws + 64 * MB);
  bf16_t* Pfd  = (bf16_t*)(ws + 80 * MB);

  const int M = BATCH * SEQ;  // 4096
  dim3 blk(256);
  const float qscale = 0.125f * LOG2E;

  // all fp32->bf16 conversions in ONE dispatch
  cvt_all<<<dim3(8192), blk, 0, stream>>>(
      src, srcB, qw, kw, vw, ow, Wqkv, OWb, w1, W1b, w2, W2b);

  // QKV: N=3072 (gxs=3), 768 blocks
  gemm_lds<3><<<dim3(768), blk, 0, stream>>>(
      srcB, Wqkv, qb, kb, vb, Qw, Kw, Vt, (bf16_t*)0,
      3072, 1024, 1024, 1024, 0, qscale, 3);
  attn_fwd<<<dim3(512), blk, 0, stream>>>(Qw, Kw, Vt, A1);
  // o-proj: N=1024 (gxs=1), split-K4, 1024 blocks (4/CU)
  gemm_lds<4><<<dim3(1024), blk, 0, stream>>>(
      A1, OWb, ob, ob, ob, Poa, Pob, Poc, Pod,
      1024, 256, 1024, 1024, 0, 1.f, 1);
  add_ln<1, 0, 1><<<dim3(M), blk, 0, stream>>>(
      src, Poa, Pob, Poc, Pod, ob, gam1, bet1, X1);
  // FF1: N=4096 (gxs=4), 1024 blocks
  gemm_lds<0><<<dim3(1024), blk, 0, stream>>>(
      X1, W1b, b1, b1, b1, F1, F1, F1, (bf16_t*)0,
      4096, 1024, 1024, 1024, 1, 1.f, 4);
  // FF2: N=1024 (gxs=1), split-K4, 1024 blocks (4/CU)
  gemm_lds<4><<<dim3(1024), blk, 0, stream>>>(
      F1, W2b, b2, b2, b2, Pfa, Pfb, Pfc, Pfd,
      1024, 1024, 4096, 4096, 0, 1.f, 1);
  add_ln<0, 1, 1><<<dim3(M), blk, 0, stream>>>(
      X1, Pfa, Pfb, Pfc, Pfd, b2, gam2, bet2, d_out);
}